// Round 15
// baseline (536.457 us; speedup 1.0000x reference)
//
#include <hip/hip_runtime.h>
#include <hip/hip_cooperative_groups.h>
#include <math.h>

namespace cg = cooperative_groups;

// Problem constants (fixed by harness)
#define NN   128
#define TT   1024
#define SS   1024
#define H1D  512
#define H2D  128
#define OUTD 8
#define KQN  8

// NUFFT constants (validated R9/R11/R14, absmax 0.0039)
#define MR    2048
#define WHALF 5
#define ALPHA 0.3702402f           // pi/sqrt(72)
#define BETA  6.35556e-6f          // pi^2/(ALPHA*MR^2)
#define DSCALE 0.3432943f          // sqrt(ALPHA/pi)
#define CSP   4

// ws layout in floats (~11.3 MB)
#define OFF_PART 0                          // [4 c][128 n][2048] float2 partials
#define OFF_FREQ (CSP*NN*MR*2)              // 2097152: freq [n][s]
#define OFF_P1   (OFF_FREQ + NN*SS)         // 2228224: P1 [8 kq][128 n][512 j]
#define OFF_H1   (OFF_P1 + KQN*NN*H1D)      // 2752512: h1 [n][512]
#define OFF_H2   (OFF_H1 + NN*H1D)          // 2818048: h2 [n][128]

__device__ __forceinline__ float cos_rev(float r) { return __builtin_amdgcn_cosf(r); } // cos(2*pi*r)
__device__ __forceinline__ float sin_rev(float r) { return __builtin_amdgcn_sinf(r); } // sin(2*pi*r)

__device__ __forceinline__ float wave_sum(float v) {
#pragma unroll
    for (int off = 32; off > 0; off >>= 1) v += __shfl_xor(v, off, 64);
    return v;
}

// ---------------------------------------------------------------------------
// COOPERATIVE single-dispatch pipeline. 512 blocks x 256 threads (2/CU,
// 32 KB LDS each). Phases (all bodies R14-verbatim math) separated by
// grid.sync(); __threadfence() gives device-scope release across XCD L2s.
//  P1 spread (512 blk: c=bid&3, n=bid>>2)  -> partial grids
//  P2 FFT+deconv (128 blk, 4 butterflies/thread) -> freq
//  P3 l1p split-K (512 blk = 8kq x 4jq x 16nb)  -> P1 partials
//  P4 l1c (+bias+sigmoid, 256 blk)              -> h1
//  P5 l2 (2048 waves x 8 tasks)                 -> h2
//  P6 l3 (1024 waves)                           -> out
// ---------------------------------------------------------------------------
__global__ __launch_bounds__(256) void k_all(const float* __restrict__ inp,
                                             const float* __restrict__ W1,
                                             const float* __restrict__ b1,
                                             const float* __restrict__ W2,
                                             const float* __restrict__ b2,
                                             const float* __restrict__ W3,
                                             const float* __restrict__ b3,
                                             float* __restrict__ out,
                                             float* __restrict__ ws) {
    cg::grid_group grid = cg::this_grid();
    const int bid = blockIdx.x;
    const int tid = threadIdx.x;

    __shared__ float4 SH[2048];   // 32 KB, re-purposed per phase

    // ================= P1: twist + Gaussian spread =================
    {
        float2* G = (float2*)SH;   // [2048]
#pragma unroll
        for (int v = 0; v < 8; ++v) G[v * 256 + tid] = make_float2(0.f, 0.f);
        float T[12];
#pragma unroll
        for (int k = 0; k < 12; ++k) {
            const int kk = k - WHALF;
            T[k] = __expf(-ALPHA * (float)(kk * kk));
        }
        __syncthreads();

        const int c = bid & 3, n = bid >> 2;
        const int t = c * 256 + tid;
        const float* p = inp + (size_t)(n * TT + t) * 3;
        const float x  = p[0];
        const float d  = p[2];
        const float df = d - floorf(d);            // exact for |d| < 2^23
        const float p512 = 512.0f * df;            // exact (pow2 scale)
        const float r512 = p512 - floorf(p512);
        const float cre = x * cos_rev(r512);
        const float cim = -x * sin_rev(r512);
        const float z  = df * 2048.0f;
        const int   j0 = (int)z;
        const float dl = z - (float)j0;
        float P = __expf(-ALPHA * dl * (dl + 10.0f));   // E1 * rho^-5
        const float R = __expf(2.0f * ALPHA * dl);      // rho
#pragma unroll
        for (int k = 0; k < 12; ++k) {
            const int gi = (j0 + k - WHALF) & (MR - 1);
            const float wk = P * T[k];
            atomicAdd(&G[gi].x, wk * cre);
            atomicAdd(&G[gi].y, wk * cim);
            P *= R;
        }
        __syncthreads();

        float2* PART = (float2*)(ws + OFF_PART) + ((size_t)c * NN + n) * MR;
#pragma unroll
        for (int v = 0; v < 8; ++v) PART[v * 256 + tid] = G[v * 256 + tid];
    }
    __threadfence();
    grid.sync();

    // ================= P2: sum partials + Stockham FFT + deconvolve ========
    if (bid < NN) {
        const int n = bid;
        float2* Ag = (float2*)SH;
        float2* Bg = ((float2*)SH) + 2048;
        const float2* PART = (const float2*)(ws + OFF_PART);
#pragma unroll
        for (int v = 0; v < 8; ++v) {
            const int bin = v * 256 + tid;
            float2 s = make_float2(0.f, 0.f);
#pragma unroll
            for (int c = 0; c < CSP; ++c) {
                const float2 a = PART[((size_t)c * NN + n) * MR + bin];
                s.x += a.x; s.y += a.y;
            }
            Ag[bin] = s;
        }
        __syncthreads();

        float2* src = Ag;
        float2* dst = Bg;
#pragma unroll
        for (int s = 0; s < 11; ++s) {
            const int   m     = 1 << s;
            const float inv2l = 1.0f / (float)(2048 >> s);
#pragma unroll
            for (int u = 0; u < 4; ++u) {
                const int tau = u * 256 + tid;
                const int j   = tau >> s;
                const float r = (float)j * inv2l;
                const float cv = cos_rev(r), sv = sin_rev(r);  // w = cv - i*sv
                const float2 a = src[tau];
                const float2 b = src[tau + 1024];
                const int o = tau + (tau & ~(m - 1));
                dst[o] = make_float2(a.x + b.x, a.y + b.y);
                const float dr = a.x - b.x, di = a.y - b.y;
                dst[o + m] = make_float2(fmaf(di, sv, dr * cv),
                                         fmaf(di, cv, -dr * sv));
            }
            __syncthreads();
            float2* tmp = src; src = dst; dst = tmp;
        }

#pragma unroll
        for (int u = 0; u < 4; ++u) {
            const int ss_ = u * 256 + tid;
            const int sp  = ss_ - 512;
            const int bin = (ss_ + 1536) & (MR - 1);
            const float2 v = src[bin];
            const float D = DSCALE * __expf(BETA * (float)(sp * sp));
            ws[OFF_FREQ + (size_t)n * SS + ss_] = sqrtf(fmaf(v.x, v.x, v.y * v.y)) * D;
        }
    }
    __threadfence();
    grid.sync();

    // ================= P3: layer-1 split-K partial GEMM ====================
    {
        const int kq = bid >> 6;          // 0..7
        const int jq = (bid >> 4) & 3;    // 0..3
        const int nb = bid & 15;          // 0..15
        float4 (*Al)[32] = (float4(*)[32])SH;   // 8 n-rows x 128 k
        const float4* FQ = (const float4*)(ws + OFF_FREQ);
        {
            const int row = tid >> 5, c4 = tid & 31;
            Al[row][c4] = FQ[(nb * 8 + row) * 256 + kq * 32 + c4];
        }
        __syncthreads();

        const int jl = tid & 127, ng = tid >> 7;
        const int j = jq * 128 + jl;
        const float4* W1v = (const float4*)W1;
        float a0 = 0.f, a1 = 0.f, a2 = 0.f, a3 = 0.f;
#pragma unroll 4
        for (int k4 = 0; k4 < 32; ++k4) {
            const float4 w  = W1v[(size_t)j * 256 + kq * 32 + k4];
            const float4 x0 = Al[ng * 4 + 0][k4];
            const float4 x1 = Al[ng * 4 + 1][k4];
            const float4 x2 = Al[ng * 4 + 2][k4];
            const float4 x3 = Al[ng * 4 + 3][k4];
            a0 = fmaf(x0.x, w.x, fmaf(x0.y, w.y, fmaf(x0.z, w.z, fmaf(x0.w, w.w, a0))));
            a1 = fmaf(x1.x, w.x, fmaf(x1.y, w.y, fmaf(x1.z, w.z, fmaf(x1.w, w.w, a1))));
            a2 = fmaf(x2.x, w.x, fmaf(x2.y, w.y, fmaf(x2.z, w.z, fmaf(x2.w, w.w, a2))));
            a3 = fmaf(x3.x, w.x, fmaf(x3.y, w.y, fmaf(x3.z, w.z, fmaf(x3.w, w.w, a3))));
        }
        float* P1 = ws + OFF_P1;
        const float acc[4] = {a0, a1, a2, a3};
#pragma unroll
        for (int i = 0; i < 4; ++i)
            P1[((size_t)(kq * NN + nb * 8 + ng * 4 + i)) * H1D + j] = acc[i];
        __syncthreads();
    }
    __threadfence();
    grid.sync();

    // ================= P4: combine + bias + sigmoid -> h1 ==================
    if (bid < 256) {
        const int idx = bid * 256 + tid;         // = n*H1D + j
        const int j = idx & (H1D - 1);
        float s = b1[j];
#pragma unroll
        for (int kq = 0; kq < KQN; ++kq) s += ws[OFF_P1 + (size_t)kq * (NN * H1D) + idx];
        ws[OFF_H1 + idx] = 1.0f / (1.0f + __expf(-s));
    }
    __threadfence();
    grid.sync();

    // ================= P5: layer-2 (2048 waves x 8 tasks) ==================
    {
        const int gw   = bid * 4 + (tid >> 6);   // 0..2047
        const int lane = tid & 63;
#pragma unroll
        for (int r = 0; r < 8; ++r) {
            const int task = r * 2048 + gw;      // 0..16383
            const int n = task >> 7, j = task & 127;
            const float4* W2v = (const float4*)W2 + (size_t)j * 128;
            const float4* H1v = (const float4*)(ws + OFF_H1) + (size_t)n * 128;
            const float4 wa = W2v[lane],      wb = W2v[64 + lane];
            const float4 ha = H1v[lane],      hb = H1v[64 + lane];
            float a = fmaf(wa.x, ha.x, fmaf(wa.y, ha.y, fmaf(wa.z, ha.z, wa.w * ha.w)));
            a = fmaf(wb.x, hb.x, fmaf(wb.y, hb.y, fmaf(wb.z, hb.z, fmaf(wb.w, hb.w, a))));
            a = wave_sum(a);
            if (lane == 0)
                ws[OFF_H2 + (size_t)n * H2D + j] = 1.0f / (1.0f + __expf(-(a + b2[j])));
        }
    }
    __threadfence();
    grid.sync();

    // ================= P6: layer-3 (1024 waves) ============================
    {
        const int gw   = bid * 4 + (tid >> 6);
        const int lane = tid & 63;
        if (gw < NN * OUTD) {
            const int n = gw >> 3, j = gw & 7;
            const float2 w = ((const float2*)W3)[j * 64 + lane];
            const float2 h = ((const float2*)(ws + OFF_H2 + (size_t)n * H2D))[lane];
            float a = fmaf(w.x, h.x, w.y * h.y);
            a = wave_sum(a);
            if (lane == 0) out[n * OUTD + j] = a + b3[j];
        }
    }
}

extern "C" void kernel_launch(void* const* d_in, const int* in_sizes, int n_in,
                              void* d_out, int out_size, void* d_ws, size_t ws_size,
                              hipStream_t stream) {
    (void)in_sizes; (void)n_in; (void)out_size; (void)ws_size;
    const float* inp = (const float*)d_in[0];
    const float* W1  = (const float*)d_in[1];
    const float* b1  = (const float*)d_in[2];
    const float* W2  = (const float*)d_in[3];
    const float* b2  = (const float*)d_in[4];
    const float* W3  = (const float*)d_in[5];
    const float* b3  = (const float*)d_in[6];
    float* out = (float*)d_out;
    float* ws  = (float*)d_ws;

    void* args[] = { (void*)&inp, (void*)&W1, (void*)&b1, (void*)&W2, (void*)&b2,
                     (void*)&W3, (void*)&b3, (void*)&out, (void*)&ws };
    hipLaunchCooperativeKernel((const void*)k_all, dim3(512), dim3(256),
                               args, 0, stream);
}

// Round 16
// 56.649 us; speedup vs baseline: 9.4699x; 9.4699x over previous
//
#include <hip/hip_runtime.h>
#include <math.h>

// Problem constants (fixed by harness)
#define NN   128
#define TT   1024
#define SS   1024
#define H1D  512
#define H2D  128
#define OUTD 8
#define KQN  8      // layer-1 split-K chunks

// NUFFT constants (validated R9/R11/R14/R15, absmax 0.0039)
#define MR    2048
#define WHALF 5
#define ALPHA 0.3702402f           // pi/sqrt(72)
#define BETA  6.35556e-6f          // pi^2/(ALPHA*MR^2)
#define DSCALE 0.3432943f          // sqrt(ALPHA/pi)

// ws layout in floats (~2.6 MB)
#define OFF_FREQ 0                          // freq [n][s]
#define OFF_P1   (NN*SS)                    // 131072: P1 [8 kq][128 n][512 j]
// end: OFF_P1 + 8*128*512 = 655360

__device__ __forceinline__ float cos_rev(float r) { return __builtin_amdgcn_cosf(r); } // cos(2*pi*r)
__device__ __forceinline__ float sin_rev(float r) { return __builtin_amdgcn_sinf(r); } // sin(2*pi*r)

__device__ __forceinline__ float wave_sum(float v) {
#pragma unroll
    for (int off = 32; off > 0; off >>= 1) v += __shfl_xor(v, off, 64);
    return v;
}

// ---------------------------------------------------------------------------
// Kernel 1: fused NUFFT per batch (R11-mega P1+P2, validated absmax 0.0039).
// Block n, 1024 threads: zero grid -> twist+spread (1 pt/thread, LDS atomics)
// -> 11-stage Stockham FFT (1 butterfly/thread) -> deconvolve -> freq[n][*].
// ---------------------------------------------------------------------------
__global__ __launch_bounds__(1024) void k_nufft(const float* __restrict__ inp,
                                                float* __restrict__ ws) {
    const int n   = blockIdx.x;
    const int tid = threadIdx.x;          // 0..1023

    __shared__ float2 Ag[MR];             // 16 KB
    __shared__ float2 Bg[MR];             // 16 KB

    Ag[tid] = make_float2(0.f, 0.f);
    Ag[tid + 1024] = make_float2(0.f, 0.f);

    float T[12];
#pragma unroll
    for (int k = 0; k < 12; ++k) {
        const int kk = k - WHALF;
        T[k] = __expf(-ALPHA * (float)(kk * kk));
    }
    __syncthreads();

    // twist + spread
    {
        const float* p = inp + (size_t)(n * TT + tid) * 3;
        const float x  = p[0];
        const float d  = p[2];
        const float df = d - floorf(d);            // exact for |d| < 2^23
        const float p512 = 512.0f * df;            // exact (pow2 scale)
        const float r512 = p512 - floorf(p512);
        const float cre = x * cos_rev(r512);
        const float cim = -x * sin_rev(r512);
        const float z  = df * 2048.0f;
        const int   j0 = (int)z;
        const float dl = z - (float)j0;
        float P = __expf(-ALPHA * dl * (dl + 10.0f));   // E1 * rho^-5
        const float R = __expf(2.0f * ALPHA * dl);      // rho
#pragma unroll
        for (int k = 0; k < 12; ++k) {
            const int gi = (j0 + k - WHALF) & (MR - 1);
            const float wk = P * T[k];
            atomicAdd(&Ag[gi].x, wk * cre);
            atomicAdd(&Ag[gi].y, wk * cim);
            P *= R;
        }
    }
    __syncthreads();

    // Stockham radix-2 FFT, N=2048, 11 stages, 1 butterfly/thread
    float2* src = Ag;
    float2* dst = Bg;
#pragma unroll
    for (int s = 0; s < 11; ++s) {
        const int   m     = 1 << s;
        const float inv2l = 1.0f / (float)(2048 >> s);
        const int tau = tid;
        const int j   = tau >> s;
        const float r = (float)j * inv2l;
        const float cv = cos_rev(r), sv = sin_rev(r);  // w = cv - i*sv
        const float2 a = src[tau];
        const float2 b = src[tau + 1024];
        const int o = tau + (tau & ~(m - 1));
        dst[o] = make_float2(a.x + b.x, a.y + b.y);
        const float dr = a.x - b.x, di = a.y - b.y;
        dst[o + m] = make_float2(fmaf(di, sv, dr * cv),
                                 fmaf(di, cv, -dr * sv));
        __syncthreads();
        float2* tmp = src; src = dst; dst = tmp;
    }

    // deconvolve + magnitude
    {
        const int ss = tid;
        const int sp = ss - 512;
        const int bin = (ss + 1536) & (MR - 1);
        const float2 v = src[bin];
        const float D = DSCALE * __expf(BETA * (float)(sp * sp));
        ws[OFF_FREQ + (size_t)n * SS + ss] = sqrtf(fmaf(v.x, v.x, v.y * v.y)) * D;
    }
}

// ---------------------------------------------------------------------------
// Kernel 2: layer-1 split-K partial GEMM (R12/R14 verbatim)
// ---------------------------------------------------------------------------
__global__ __launch_bounds__(256) void k_l1p(const float* __restrict__ W1,
                                             float* __restrict__ ws) {
    const int kq = blockIdx.x;   // 0..7   k-chunk of 128
    const int jq = blockIdx.y;   // 0..3   j-chunk of 128
    const int nb = blockIdx.z;   // 0..15  n-chunk of 8
    const int tid = threadIdx.x;

    __shared__ float4 Al[8][32];  // 8 n-rows x 128 k (as float4)
    const float4* FQ = (const float4*)(ws + OFF_FREQ);
    {
        const int row = tid >> 5, c4 = tid & 31;
        Al[row][c4] = FQ[(nb * 8 + row) * 256 + kq * 32 + c4];
    }
    __syncthreads();

    const int jl = tid & 127, ng = tid >> 7;
    const int j = jq * 128 + jl;
    const float4* W1v = (const float4*)W1;
    float a0 = 0.f, a1 = 0.f, a2 = 0.f, a3 = 0.f;
#pragma unroll 4
    for (int k4 = 0; k4 < 32; ++k4) {
        const float4 w  = W1v[(size_t)j * 256 + kq * 32 + k4];
        const float4 x0 = Al[ng * 4 + 0][k4];
        const float4 x1 = Al[ng * 4 + 1][k4];
        const float4 x2 = Al[ng * 4 + 2][k4];
        const float4 x3 = Al[ng * 4 + 3][k4];
        a0 = fmaf(x0.x, w.x, fmaf(x0.y, w.y, fmaf(x0.z, w.z, fmaf(x0.w, w.w, a0))));
        a1 = fmaf(x1.x, w.x, fmaf(x1.y, w.y, fmaf(x1.z, w.z, fmaf(x1.w, w.w, a1))));
        a2 = fmaf(x2.x, w.x, fmaf(x2.y, w.y, fmaf(x2.z, w.z, fmaf(x2.w, w.w, a2))));
        a3 = fmaf(x3.x, w.x, fmaf(x3.y, w.y, fmaf(x3.z, w.z, fmaf(x3.w, w.w, a3))));
    }
    float* P1 = ws + OFF_P1;
    const float acc[4] = {a0, a1, a2, a3};
#pragma unroll
    for (int i = 0; i < 4; ++i)
        P1[((size_t)(kq * NN + nb * 8 + ng * 4 + i)) * H1D + j] = acc[i];
}

// ---------------------------------------------------------------------------
// Kernel 3: fused MLP tail per batch n (l1c + l2 + l3), 1024 threads.
//  l1c: threads 0..511 -> h1[j] = sigmoid(bias + sum_kq P1) into LDS
//  l2 : 16 waves x 8 j; W2 rows coalesced from L2, h1 from LDS, shfl reduce
//  l3 : waves 0..7, one output each
// ---------------------------------------------------------------------------
__global__ __launch_bounds__(1024) void k_mlp2(const float* __restrict__ b1,
                                               const float* __restrict__ W2,
                                               const float* __restrict__ b2,
                                               const float* __restrict__ W3,
                                               const float* __restrict__ b3,
                                               const float* __restrict__ ws,
                                               float* __restrict__ out) {
    const int n   = blockIdx.x;
    const int tid = threadIdx.x;
    const int wid = tid >> 6, lane = tid & 63;

    __shared__ float h1L[H1D];
    __shared__ float h2L[H2D];

    if (tid < H1D) {
        const int j = tid;
        float s = b1[j];
#pragma unroll
        for (int kq = 0; kq < KQN; ++kq)
            s += ws[OFF_P1 + ((size_t)kq * NN + n) * H1D + j];
        h1L[j] = 1.0f / (1.0f + __expf(-s));
    }
    __syncthreads();

    // layer 2: wave wid handles j = wid*8 .. wid*8+7
    {
        const float4* H1v = (const float4*)h1L;
        const float4 ha = H1v[lane], hb = H1v[64 + lane];
#pragma unroll
        for (int q = 0; q < 8; ++q) {
            const int j = wid * 8 + q;
            const float4* W2v = (const float4*)W2 + (size_t)j * 128;
            const float4 wa = W2v[lane], wb = W2v[64 + lane];
            float a = fmaf(wa.x, ha.x, fmaf(wa.y, ha.y, fmaf(wa.z, ha.z, wa.w * ha.w)));
            a = fmaf(wb.x, hb.x, fmaf(wb.y, hb.y, fmaf(wb.z, hb.z, fmaf(wb.w, hb.w, a))));
            a = wave_sum(a);
            if (lane == 0) h2L[j] = 1.0f / (1.0f + __expf(-(a + b2[j])));
        }
    }
    __syncthreads();

    // layer 3: waves 0..7, one output each
    if (wid < OUTD) {
        const float2 w = ((const float2*)W3)[wid * 64 + lane];
        const float2 h = ((const float2*)h2L)[lane];
        float a = fmaf(w.x, h.x, w.y * h.y);
        a = wave_sum(a);
        if (lane == 0) out[n * OUTD + wid] = a + b3[wid];
    }
}

extern "C" void kernel_launch(void* const* d_in, const int* in_sizes, int n_in,
                              void* d_out, int out_size, void* d_ws, size_t ws_size,
                              hipStream_t stream) {
    (void)in_sizes; (void)n_in; (void)out_size; (void)ws_size;
    const float* inp = (const float*)d_in[0];
    const float* W1  = (const float*)d_in[1];
    const float* b1  = (const float*)d_in[2];
    const float* W2  = (const float*)d_in[3];
    const float* b2  = (const float*)d_in[4];
    const float* W3  = (const float*)d_in[5];
    const float* b3  = (const float*)d_in[6];
    float* out = (float*)d_out;
    float* ws  = (float*)d_ws;

    k_nufft<<<dim3(NN),      dim3(1024), 0, stream>>>(inp, ws);
    k_l1p  <<<dim3(8, 4, 16),dim3(256),  0, stream>>>(W1, ws);
    k_mlp2 <<<dim3(NN),      dim3(1024), 0, stream>>>(b1, W2, b2, W3, b3, ws, out);
}

// Round 17
// 52.722 us; speedup vs baseline: 10.1753x; 1.0745x over previous
//
#include <hip/hip_runtime.h>
#include <math.h>

// Problem constants (fixed by harness)
#define NN   128
#define TT   1024
#define SS   1024
#define H1D  512
#define H2D  128
#define OUTD 8

// NUFFT constants (validated R9/R11/R14, absmax 0.0039)
#define MR    2048
#define WHALF 5
#define ALPHA 0.3702402f           // pi/sqrt(72)
#define BETA  6.35556e-6f          // pi^2/(ALPHA*MR^2)
#define DSCALE 0.3432943f          // sqrt(ALPHA/pi)
#define CSP   4

// ws layout in floats (8.4 MB)
#define OFF_PART 0                 // [4 c][128 n][2048] float2 partial grids

__device__ __forceinline__ float cos_rev(float r) { return __builtin_amdgcn_cosf(r); } // cos(2*pi*r)
__device__ __forceinline__ float sin_rev(float r) { return __builtin_amdgcn_sinf(r); } // sin(2*pi*r)

__device__ __forceinline__ float wave_sum(float v) {
#pragma unroll
    for (int off = 32; off > 0; off >>= 1) v += __shfl_xor(v, off, 64);
    return v;
}

// ---------------------------------------------------------------------------
// Kernel 1: twist + Gaussian spread into partial grids (R14 verbatim).
// 512 blocks x 256 thr (2/CU): best-measured spread config.
// ---------------------------------------------------------------------------
__global__ __launch_bounds__(256) void k_spread(const float* __restrict__ inp,
                                                float* __restrict__ ws) {
    const int c   = blockIdx.x;    // 0..3
    const int n   = blockIdx.y;    // 0..127
    const int tid = threadIdx.x;   // 0..255

    __shared__ float2 G[MR];       // 16 KB
#pragma unroll
    for (int v = 0; v < MR / 256; ++v) G[v * 256 + tid] = make_float2(0.f, 0.f);

    float T[12];
#pragma unroll
    for (int k = 0; k < 12; ++k) {
        const int kk = k - WHALF;
        T[k] = __expf(-ALPHA * (float)(kk * kk));
    }
    __syncthreads();

    {
        const int t = c * 256 + tid;
        const float* p = inp + (size_t)(n * TT + t) * 3;
        const float x  = p[0];
        const float d  = p[2];
        const float df = d - floorf(d);            // exact for |d| < 2^23
        const float p512 = 512.0f * df;            // exact (pow2 scale)
        const float r512 = p512 - floorf(p512);
        const float cre = x * cos_rev(r512);
        const float cim = -x * sin_rev(r512);
        const float z  = df * 2048.0f;             // [0,2048)
        const int   j0 = (int)z;
        const float dl = z - (float)j0;
        float P = __expf(-ALPHA * dl * (dl + 10.0f));   // E1 * rho^-5
        const float R = __expf(2.0f * ALPHA * dl);      // rho
#pragma unroll
        for (int k = 0; k < 12; ++k) {
            const int gi = (j0 + k - WHALF) & (MR - 1);
            const float wk = P * T[k];
            atomicAdd(&G[gi].x, wk * cre);
            atomicAdd(&G[gi].y, wk * cim);
            P *= R;
        }
    }
    __syncthreads();

    float2* PART = (float2*)(ws + OFF_PART) + ((size_t)c * NN + n) * MR;
#pragma unroll
    for (int v = 0; v < MR / 256; ++v) PART[v * 256 + tid] = G[v * 256 + tid];
}

// ---------------------------------------------------------------------------
// Kernel 2: everything else, block-local per batch n (128 blk x 1024 thr).
//  A) sum 4 partial grids -> Ag           (R14 k_fft verbatim)
//  B) 11-stage Stockham FFT, 1 bfly/thr   (R11/R14 verbatim)
//  C) deconvolve + magnitude -> freq LDS  (R11 verbatim)
//  D) layer-1 wave-per-row, full K=1024   (R11-mega verified 4-chunk code)
//  E) layer-2, F) layer-3                 (R11/R16 verbatim)
// No P1 buffer, no freq global roundtrip, no split-K combine.
// ---------------------------------------------------------------------------
__global__ __launch_bounds__(1024) void k_rest(const float* __restrict__ W1,
                                               const float* __restrict__ b1,
                                               const float* __restrict__ W2,
                                               const float* __restrict__ b2,
                                               const float* __restrict__ W3,
                                               const float* __restrict__ b3,
                                               const float* __restrict__ ws,
                                               float* __restrict__ out) {
    const int n   = blockIdx.x;
    const int tid = threadIdx.x;          // 0..1023
    const int wid = tid >> 6, lane = tid & 63;

    __shared__ float2 Ag[MR];             // 16 KB (later freq/h1/h2 overlay)
    __shared__ float2 Bg[MR];             // 16 KB

    // ---- A) sum partials ----
    {
        const float2* PART = (const float2*)(ws + OFF_PART);
        float2 s0 = make_float2(0.f, 0.f), s1 = make_float2(0.f, 0.f);
#pragma unroll
        for (int c = 0; c < CSP; ++c) {
            const float2* P = PART + ((size_t)c * NN + n) * MR;
            const float2 a = P[tid];
            const float2 b = P[tid + 1024];
            s0.x += a.x; s0.y += a.y;
            s1.x += b.x; s1.y += b.y;
        }
        Ag[tid] = s0;
        Ag[tid + 1024] = s1;
    }
    __syncthreads();

    // ---- B) Stockham radix-2 FFT, N=2048, 11 stages ----
    float2* src = Ag;
    float2* dst = Bg;
#pragma unroll
    for (int s = 0; s < 11; ++s) {
        const int   m     = 1 << s;
        const float inv2l = 1.0f / (float)(2048 >> s);
        const int tau = tid;
        const int j   = tau >> s;
        const float r = (float)j * inv2l;
        const float cv = cos_rev(r), sv = sin_rev(r);  // w = cv - i*sv
        const float2 a = src[tau];
        const float2 b = src[tau + 1024];
        const int o = tau + (tau & ~(m - 1));
        dst[o] = make_float2(a.x + b.x, a.y + b.y);
        const float dr = a.x - b.x, di = a.y - b.y;
        dst[o + m] = make_float2(fmaf(di, sv, dr * cv),
                                 fmaf(di, cv, -dr * sv));
        __syncthreads();
        float2* tmp = src; src = dst; dst = tmp;
    }
    // after 11 swaps: data in Bg (src==Bg), Ag free for overlay

    float* freqL = (float*)Ag;            // [1024]
    float* h1L   = freqL + SS;            // [512]
    float* h2L   = h1L + H1D;             // [128]  (1664 floats < 4096)

    // ---- C) deconvolve + magnitude ----
    {
        const int ss = tid;
        const int sp = ss - 512;
        const int bin = (ss + 1536) & (MR - 1);
        const float2 v = src[bin];
        const float D = DSCALE * __expf(BETA * (float)(sp * sp));
        freqL[ss] = sqrtf(fmaf(v.x, v.x, v.y * v.y)) * D;
    }
    __syncthreads();

    // ---- D) layer 1: 16 waves x 32 rows, full K=1024 (4 chunks/lane) ----
    {
        const float4* F4 = (const float4*)freqL;
        const float4 fq0 = F4[lane];
        const float4 fq1 = F4[64 + lane];
        const float4 fq2 = F4[128 + lane];
        const float4 fq3 = F4[192 + lane];
        const float4* W1v = (const float4*)W1;
#pragma unroll 2
        for (int jj = 0; jj < 32; ++jj) {
            const int j = wid * 32 + jj;
            const float4* Wr = W1v + (size_t)j * 256;
            const float4 w0 = Wr[lane];
            const float4 w1 = Wr[64 + lane];
            const float4 w2 = Wr[128 + lane];
            const float4 w3 = Wr[192 + lane];
            float a = fmaf(w0.x, fq0.x, fmaf(w0.y, fq0.y, fmaf(w0.z, fq0.z, w0.w * fq0.w)));
            a = fmaf(w1.x, fq1.x, fmaf(w1.y, fq1.y, fmaf(w1.z, fq1.z, fmaf(w1.w, fq1.w, a))));
            a = fmaf(w2.x, fq2.x, fmaf(w2.y, fq2.y, fmaf(w2.z, fq2.z, fmaf(w2.w, fq2.w, a))));
            a = fmaf(w3.x, fq3.x, fmaf(w3.y, fq3.y, fmaf(w3.z, fq3.z, fmaf(w3.w, fq3.w, a))));
            a = wave_sum(a);
            if (lane == 0) h1L[j] = 1.0f / (1.0f + __expf(-(a + b1[j])));
        }
    }
    __syncthreads();

    // ---- E) layer 2: 16 waves x 8 rows, K=512 (2 chunks/lane) ----
    {
        const float4* H1v = (const float4*)h1L;
        const float4 ha = H1v[lane], hb = H1v[64 + lane];
#pragma unroll 2
        for (int q = 0; q < 8; ++q) {
            const int j = wid * 8 + q;
            const float4* W2v = (const float4*)W2 + (size_t)j * 128;
            const float4 wa = W2v[lane], wb = W2v[64 + lane];
            float a = fmaf(wa.x, ha.x, fmaf(wa.y, ha.y, fmaf(wa.z, ha.z, wa.w * ha.w)));
            a = fmaf(wb.x, hb.x, fmaf(wb.y, hb.y, fmaf(wb.z, hb.z, fmaf(wb.w, hb.w, a))));
            a = wave_sum(a);
            if (lane == 0) h2L[j] = 1.0f / (1.0f + __expf(-(a + b2[j])));
        }
    }
    __syncthreads();

    // ---- F) layer 3: waves 0..7, one output each ----
    if (wid < OUTD) {
        const float2 w = ((const float2*)W3)[wid * 64 + lane];
        const float2 h = ((const float2*)h2L)[lane];
        float a = fmaf(w.x, h.x, w.y * h.y);
        a = wave_sum(a);
        if (lane == 0) out[n * OUTD + wid] = a + b3[wid];
    }
}

extern "C" void kernel_launch(void* const* d_in, const int* in_sizes, int n_in,
                              void* d_out, int out_size, void* d_ws, size_t ws_size,
                              hipStream_t stream) {
    (void)in_sizes; (void)n_in; (void)out_size; (void)ws_size;
    const float* inp = (const float*)d_in[0];
    const float* W1  = (const float*)d_in[1];
    const float* b1  = (const float*)d_in[2];
    const float* W2  = (const float*)d_in[3];
    const float* b2  = (const float*)d_in[4];
    const float* W3  = (const float*)d_in[5];
    const float* b3  = (const float*)d_in[6];
    float* out = (float*)d_out;
    float* ws  = (float*)d_ws;

    k_spread<<<dim3(CSP, NN), dim3(256),  0, stream>>>(inp, ws);
    k_rest  <<<dim3(NN),      dim3(1024), 0, stream>>>(W1, b1, W2, b2, W3, b3, ws, out);
}

// Round 18
// 50.848 us; speedup vs baseline: 10.5502x; 1.0368x over previous
//
#include <hip/hip_runtime.h>
#include <math.h>

// Problem constants (fixed by harness)
#define NN   128
#define TT   1024
#define SS   1024
#define H1D  512
#define H2D  128
#define OUTD 8
#define KQN  8      // layer-1 split-K chunks

// NUFFT constants (validated R9/R11/R14, absmax 0.0039)
#define MR    2048
#define WHALF 5
#define ALPHA 0.3702402f           // pi/sqrt(72)
#define BETA  6.35556e-6f          // pi^2/(ALPHA*MR^2)
#define DSCALE 0.3432943f          // sqrt(ALPHA/pi)
#define CSP   4

// ws layout in floats (~13.4 MB)
#define OFF_PART 0                          // [4 c][128 n][2048] float2, DECIMATED: PART[r*512+q] = g[4q+r]
#define OFF_SUB  (CSP*NN*MR*2)              // 2097152: [128 n][4 r][512 q] float2 sub-FFT outputs
#define OFF_FREQ (OFF_SUB + NN*4*512*2)     // 2621440: freq [n][s]
#define OFF_P1   (OFF_FREQ + NN*SS)         // 2752512: P1 [8 kq][128 n][512 j]
#define OFF_H1   (OFF_P1 + KQN*NN*H1D)      // 3276800: h1 [n][512]
#define OFF_H2   (OFF_H1 + NN*H1D)          // 3342336: h2 [n][128]

__device__ __forceinline__ float cos_rev(float r) { return __builtin_amdgcn_cosf(r); } // cos(2*pi*r)
__device__ __forceinline__ float sin_rev(float r) { return __builtin_amdgcn_sinf(r); } // sin(2*pi*r)

__device__ __forceinline__ float wave_sum(float v) {
#pragma unroll
    for (int off = 32; off > 0; off >>= 1) v += __shfl_xor(v, off, 64);
    return v;
}

// ---------------------------------------------------------------------------
// Kernel 1: twist + Gaussian spread (R14-verbatim math). Output is written
// DECIMATED by 4: PART[c][n][r*512+q] = G[4q+r], so the sub-FFT kernel
// reads its stride-4 subsequence contiguously (coalesced).
// ---------------------------------------------------------------------------
__global__ __launch_bounds__(256) void k_spread(const float* __restrict__ inp,
                                                float* __restrict__ ws) {
    const int c   = blockIdx.x;    // 0..3
    const int n   = blockIdx.y;    // 0..127
    const int tid = threadIdx.x;   // 0..255

    __shared__ float2 G[MR];       // 16 KB
#pragma unroll
    for (int v = 0; v < MR / 256; ++v) G[v * 256 + tid] = make_float2(0.f, 0.f);

    float T[12];
#pragma unroll
    for (int k = 0; k < 12; ++k) {
        const int kk = k - WHALF;
        T[k] = __expf(-ALPHA * (float)(kk * kk));
    }
    __syncthreads();

    {
        const int t = c * 256 + tid;
        const float* p = inp + (size_t)(n * TT + t) * 3;
        const float x  = p[0];
        const float d  = p[2];
        const float df = d - floorf(d);            // exact for |d| < 2^23
        const float p512 = 512.0f * df;            // exact (pow2 scale)
        const float r512 = p512 - floorf(p512);
        const float cre = x * cos_rev(r512);
        const float cim = -x * sin_rev(r512);
        const float z  = df * 2048.0f;             // [0,2048)
        const int   j0 = (int)z;
        const float dl = z - (float)j0;
        float P = __expf(-ALPHA * dl * (dl + 10.0f));   // E1 * rho^-5
        const float R = __expf(2.0f * ALPHA * dl);      // rho
#pragma unroll
        for (int k = 0; k < 12; ++k) {
            const int gi = (j0 + k - WHALF) & (MR - 1);
            const float wk = P * T[k];
            atomicAdd(&G[gi].x, wk * cre);
            atomicAdd(&G[gi].y, wk * cim);
            P *= R;
        }
    }
    __syncthreads();

    // decimated write: PART[u] = G[(u&511)*4 + (u>>9)]  (u = r*512+q)
    float2* PART = (float2*)(ws + OFF_PART) + ((size_t)c * NN + n) * MR;
#pragma unroll
    for (int v = 0; v < MR / 256; ++v) {
        const int u = v * 256 + tid;
        const int m = ((u & 511) << 2) | (u >> 9);
        PART[u] = G[m];
    }
}

// ---------------------------------------------------------------------------
// Kernel 2: 512-pt sub-FFT. Grid (4 r, 128 n) = 512 blocks x 256 thr.
// Sums the 4 c-partials inline (coalesced: decimated layout), then 9-stage
// Stockham radix-2 (same validated pattern, N=512), writes SUB[n][r][q].
// ---------------------------------------------------------------------------
__global__ __launch_bounds__(256) void k_fft512(float* __restrict__ ws) {
    const int r   = blockIdx.x;    // 0..3
    const int n   = blockIdx.y;    // 0..127
    const int tid = threadIdx.x;   // 0..255

    __shared__ float2 Ag[512];     // 4 KB
    __shared__ float2 Bg[512];     // 4 KB

    {
        const float2* PART = (const float2*)(ws + OFF_PART);
#pragma unroll
        for (int v = 0; v < 2; ++v) {
            const int q = v * 256 + tid;
            float2 s = make_float2(0.f, 0.f);
#pragma unroll
            for (int c = 0; c < CSP; ++c) {
                const float2 a = PART[((size_t)c * NN + n) * MR + r * 512 + q];
                s.x += a.x; s.y += a.y;
            }
            Ag[q] = s;
        }
    }
    __syncthreads();

    // Stockham radix-2, N=512, 9 stages, 1 butterfly/thread (validated pattern)
    float2* src = Ag;
    float2* dst = Bg;
#pragma unroll
    for (int s = 0; s < 9; ++s) {
        const int   m    = 1 << s;
        const float invl = 1.0f / (float)(512 >> s);
        const int tau = tid;
        const int j   = tau >> s;
        const float rr = (float)j * invl;
        const float cv = cos_rev(rr), sv = sin_rev(rr);  // w = cv - i*sv
        const float2 a = src[tau];
        const float2 b = src[tau + 256];
        const int o = tau + (tau & ~(m - 1));
        dst[o] = make_float2(a.x + b.x, a.y + b.y);
        const float dr = a.x - b.x, di = a.y - b.y;
        dst[o + m] = make_float2(fmaf(di, sv, dr * cv),
                                 fmaf(di, cv, -dr * sv));
        __syncthreads();
        float2* tmp = src; src = dst; dst = tmp;
    }

    float2* SUB = (float2*)(ws + OFF_SUB) + ((size_t)n * 4 + r) * 512;
#pragma unroll
    for (int v = 0; v < 2; ++v) {
        const int q = v * 256 + tid;
        SUB[q] = src[q];
    }
}

// ---------------------------------------------------------------------------
// Kernel 3: radix-4 DIT combine + deconvolve + magnitude -> freq.
// G[k] = sum_r e^{-2pi i r k/2048} F_r[k mod 512]; k = (ss+1536)&2047,
// km = ss&511 (since 1536 = 3*512). 512 blocks x 256 thr, elementwise.
// ---------------------------------------------------------------------------
__global__ __launch_bounds__(256) void k_comb(float* __restrict__ ws) {
    const int gid = blockIdx.x * 256 + threadIdx.x;   // 0..131071
    const int n  = gid >> 10;
    const int ss = gid & 1023;
    const int k  = (ss + 1536) & (MR - 1);
    const int km = ss & 511;

    const float2* SUB = (const float2*)(ws + OFF_SUB) + (size_t)n * 4 * 512;
    const float f1 = (float)k * (1.0f / 2048.0f);     // exact (k has <=11 bits)

    float2 X = SUB[km];                               // r=0: w=1
#pragma unroll
    for (int r = 1; r < 4; ++r) {
        const float2 F = SUB[r * 512 + km];
        const float fr = (float)r * f1;
        const float ff = fr - floorf(fr);             // exact
        const float cv = cos_rev(ff), sv = sin_rev(ff);   // w = cv - i*sv
        X.x = fmaf(F.x, cv, fmaf(F.y, sv, X.x));
        X.y = fmaf(F.y, cv, fmaf(-F.x, sv, X.y));
    }

    const int sp = ss - 512;
    const float D = DSCALE * __expf(BETA * (float)(sp * sp));
    ws[OFF_FREQ + (size_t)n * SS + ss] = sqrtf(fmaf(X.x, X.x, X.y * X.y)) * D;
}

// ---------------------------------------------------------------------------
// Kernel 4: layer-1 split-K partial GEMM (R12/R14 verbatim)
// ---------------------------------------------------------------------------
__global__ __launch_bounds__(256) void k_l1p(const float* __restrict__ W1,
                                             float* __restrict__ ws) {
    const int kq = blockIdx.x;   // 0..7   k-chunk of 128
    const int jq = blockIdx.y;   // 0..3   j-chunk of 128
    const int nb = blockIdx.z;   // 0..15  n-chunk of 8
    const int tid = threadIdx.x;

    __shared__ float4 Al[8][32];  // 8 n-rows x 128 k (as float4)
    const float4* FQ = (const float4*)(ws + OFF_FREQ);
    {
        const int row = tid >> 5, c4 = tid & 31;
        Al[row][c4] = FQ[(nb * 8 + row) * 256 + kq * 32 + c4];
    }
    __syncthreads();

    const int jl = tid & 127, ng = tid >> 7;
    const int j = jq * 128 + jl;
    const float4* W1v = (const float4*)W1;
    float a0 = 0.f, a1 = 0.f, a2 = 0.f, a3 = 0.f;
#pragma unroll 4
    for (int k4 = 0; k4 < 32; ++k4) {
        const float4 w  = W1v[(size_t)j * 256 + kq * 32 + k4];
        const float4 x0 = Al[ng * 4 + 0][k4];
        const float4 x1 = Al[ng * 4 + 1][k4];
        const float4 x2 = Al[ng * 4 + 2][k4];
        const float4 x3 = Al[ng * 4 + 3][k4];
        a0 = fmaf(x0.x, w.x, fmaf(x0.y, w.y, fmaf(x0.z, w.z, fmaf(x0.w, w.w, a0))));
        a1 = fmaf(x1.x, w.x, fmaf(x1.y, w.y, fmaf(x1.z, w.z, fmaf(x1.w, w.w, a1))));
        a2 = fmaf(x2.x, w.x, fmaf(x2.y, w.y, fmaf(x2.z, w.z, fmaf(x2.w, w.w, a2))));
        a3 = fmaf(x3.x, w.x, fmaf(x3.y, w.y, fmaf(x3.z, w.z, fmaf(x3.w, w.w, a3))));
    }
    float* P1 = ws + OFF_P1;
    const float acc[4] = {a0, a1, a2, a3};
#pragma unroll
    for (int i = 0; i < 4; ++i)
        P1[((size_t)(kq * NN + nb * 8 + ng * 4 + i)) * H1D + j] = acc[i];
}

// ---------------------------------------------------------------------------
// Kernel 5: combine layer-1 partials + bias + sigmoid -> h1 (R12 verbatim)
// ---------------------------------------------------------------------------
__global__ __launch_bounds__(256) void k_l1c(const float* __restrict__ b1,
                                             float* __restrict__ ws) {
    const int tid = blockIdx.x * 256 + threadIdx.x;   // = n*H1D + j
    const int j = tid & (H1D - 1);
    float s = b1[j];
#pragma unroll
    for (int kq = 0; kq < KQN; ++kq) s += ws[OFF_P1 + (size_t)kq * (NN * H1D) + tid];
    ws[OFF_H1 + tid] = 1.0f / (1.0f + __expf(-s));
}

// ---------------------------------------------------------------------------
// Kernel 6: layer-2, one wave per (n,j) (R12 verbatim)
// ---------------------------------------------------------------------------
__global__ __launch_bounds__(256) void k_l2(const float* __restrict__ W2,
                                            const float* __restrict__ b2,
                                            float* __restrict__ ws) {
    const int task = blockIdx.x * 4 + (threadIdx.x >> 6);   // 0..16383
    const int lane = threadIdx.x & 63;
    const int n = task >> 7, j = task & 127;

    const float4* W2v = (const float4*)W2 + (size_t)j * 128;
    const float4* H1v = (const float4*)(ws + OFF_H1) + (size_t)n * 128;
    const float4 wa = W2v[lane],      wb = W2v[64 + lane];
    const float4 ha = H1v[lane],      hb = H1v[64 + lane];
    float a = fmaf(wa.x, ha.x, fmaf(wa.y, ha.y, fmaf(wa.z, ha.z, wa.w * ha.w)));
    a = fmaf(wb.x, hb.x, fmaf(wb.y, hb.y, fmaf(wb.z, hb.z, fmaf(wb.w, hb.w, a))));
    a = wave_sum(a);
    if (lane == 0)
        ws[OFF_H2 + (size_t)n * H2D + j] = 1.0f / (1.0f + __expf(-(a + b2[j])));
}

// ---------------------------------------------------------------------------
// Kernel 7: layer-3, one wave per (n,j) (R12 verbatim)
// ---------------------------------------------------------------------------
__global__ __launch_bounds__(256) void k_l3(const float* __restrict__ W3,
                                            const float* __restrict__ b3,
                                            const float* __restrict__ ws,
                                            float* __restrict__ out) {
    const int task = blockIdx.x * 4 + (threadIdx.x >> 6);   // 0..1023
    const int lane = threadIdx.x & 63;
    const int n = task >> 3, j = task & 7;

    const float2 w = ((const float2*)W3)[j * 64 + lane];
    const float2 h = ((const float2*)(ws + OFF_H2 + (size_t)n * H2D))[lane];
    float a = fmaf(w.x, h.x, w.y * h.y);
    a = wave_sum(a);
    if (lane == 0) out[n * OUTD + j] = a + b3[j];
}

extern "C" void kernel_launch(void* const* d_in, const int* in_sizes, int n_in,
                              void* d_out, int out_size, void* d_ws, size_t ws_size,
                              hipStream_t stream) {
    (void)in_sizes; (void)n_in; (void)out_size; (void)ws_size;
    const float* inp = (const float*)d_in[0];
    const float* W1  = (const float*)d_in[1];
    const float* b1  = (const float*)d_in[2];
    const float* W2  = (const float*)d_in[3];
    const float* b2  = (const float*)d_in[4];
    const float* W3  = (const float*)d_in[5];
    const float* b3  = (const float*)d_in[6];
    float* out = (float*)d_out;
    float* ws  = (float*)d_ws;

    k_spread<<<dim3(CSP, NN), dim3(256), 0, stream>>>(inp, ws);
    k_fft512<<<dim3(4, NN),   dim3(256), 0, stream>>>(ws);
    k_comb  <<<dim3(512),     dim3(256), 0, stream>>>(ws);
    k_l1p   <<<dim3(8, 4, 16),dim3(256), 0, stream>>>(W1, ws);
    k_l1c   <<<dim3(256),     dim3(256), 0, stream>>>(b1, ws);
    k_l2    <<<dim3(4096),    dim3(256), 0, stream>>>(W2, b2, ws);
    k_l3    <<<dim3(256),     dim3(256), 0, stream>>>(W3, b3, ws, out);
}

// Round 19
// 43.038 us; speedup vs baseline: 12.4647x; 1.1815x over previous
//
#include <hip/hip_runtime.h>
#include <math.h>

// Problem constants (fixed by harness)
#define NN   128
#define TT   1024
#define SS   1024
#define H1D  512
#define H2D  128
#define OUTD 8
#define KQN  8      // layer-1 split-K chunks

// NUFFT constants (validated R9-R18, absmax 0.0039)
#define MR    2048
#define WHALF 5
#define ALPHA 0.3702402f           // pi/sqrt(72)
#define BETA  6.35556e-6f          // pi^2/(ALPHA*MR^2)
#define DSCALE 0.3432943f          // sqrt(ALPHA/pi)

// ws layout in floats (~10.5 MB)
#define OFF_SUBT 0                          // [128 n][512 q][4 r] float2 sub-FFT outputs
#define OFF_P1   (NN*512*4*2)               // 2097152: P1 [8 kq][128 n][512 j]
// end: OFF_P1 + 8*128*512 = 2621440

__device__ __forceinline__ float cos_rev(float r) { return __builtin_amdgcn_cosf(r); } // cos(2*pi*r)
__device__ __forceinline__ float sin_rev(float r) { return __builtin_amdgcn_sinf(r); } // sin(2*pi*r)

__device__ __forceinline__ float wave_sum(float v) {
#pragma unroll
    for (int off = 32; off > 0; off >>= 1) v += __shfl_xor(v, off, 64);
    return v;
}

// ---------------------------------------------------------------------------
// Kernel 1: FUSED residue-spread + 512-pt sub-FFT. Grid (4 r, 128 n), 256 thr.
// Block (r,n) reads all 1024 points of batch n; each point contributes its 3
// Gaussian taps with bin == r (mod 4): k0 = (r+5-j0) mod 4, k in {k0,k0+4,k0+8},
// weight = exp(-ALPHA*(dl-(k-5))^2)  [== validated P0*R^k*T[k] recurrence].
// Decimated bin q = gi>>2 in a 512-bin LDS grid -> 9-stage Stockham (R18
// k_fft512 verbatim) -> SUBT[n][q][r] (r-contiguous for the combine reader).
// ---------------------------------------------------------------------------
__global__ __launch_bounds__(256) void k_sf(const float* __restrict__ inp,
                                            float* __restrict__ ws) {
    const int r   = blockIdx.x;    // 0..3
    const int n   = blockIdx.y;    // 0..127
    const int tid = threadIdx.x;   // 0..255

    __shared__ float2 Ag[512];     // 4 KB
    __shared__ float2 Bg[512];     // 4 KB

    Ag[tid] = make_float2(0.f, 0.f);
    Ag[tid + 256] = make_float2(0.f, 0.f);
    __syncthreads();

    const float* row = inp + (size_t)n * TT * 3;
#pragma unroll
    for (int pp = 0; pp < 4; ++pp) {
        const int t = pp * 256 + tid;
        const float x  = row[t * 3 + 0];
        const float d  = row[t * 3 + 2];
        const float df = d - floorf(d);            // exact for |d| < 2^23
        const float p512 = 512.0f * df;            // exact (pow2 scale)
        const float r512 = p512 - floorf(p512);
        const float cre = x * cos_rev(r512);
        const float cim = -x * sin_rev(r512);
        const float z  = df * 2048.0f;             // [0,2048)
        const int   j0 = (int)z;
        const float dl = z - (float)j0;
        const int k0 = (r + 5 - j0 + 2048) & 3;    // +2048 (mult of 4) keeps arg >0
#pragma unroll
        for (int i = 0; i < 3; ++i) {
            const int   k = k0 + 4 * i;
            const float u = dl - (float)(k - WHALF);
            const float w = __expf(-ALPHA * u * u);
            const int  gi = (j0 + k - WHALF) & (MR - 1);
            const int   q = gi >> 2;               // gi == r (mod 4)
            atomicAdd(&Ag[q].x, w * cre);
            atomicAdd(&Ag[q].y, w * cim);
        }
    }
    __syncthreads();

    // Stockham radix-2, N=512, 9 stages, 1 butterfly/thread (R18 verbatim)
    float2* src = Ag;
    float2* dst = Bg;
#pragma unroll
    for (int s = 0; s < 9; ++s) {
        const int   m    = 1 << s;
        const float invl = 1.0f / (float)(512 >> s);
        const int tau = tid;
        const int j   = tau >> s;
        const float rr = (float)j * invl;
        const float cv = cos_rev(rr), sv = sin_rev(rr);  // w = cv - i*sv
        const float2 a = src[tau];
        const float2 b = src[tau + 256];
        const int o = tau + (tau & ~(m - 1));
        dst[o] = make_float2(a.x + b.x, a.y + b.y);
        const float dr = a.x - b.x, di = a.y - b.y;
        dst[o + m] = make_float2(fmaf(di, sv, dr * cv),
                                 fmaf(di, cv, -dr * sv));
        __syncthreads();
        float2* tmp = src; src = dst; dst = tmp;
    }

    float2* SUBT = (float2*)(ws + OFF_SUBT);
    SUBT[((size_t)n * 512 + tid)       * 4 + r] = src[tid];
    SUBT[((size_t)n * 512 + tid + 256) * 4 + r] = src[tid + 256];
}

// ---------------------------------------------------------------------------
// Kernel 2: FUSED radix-4 combine+deconvolve+magnitude -> LDS tile -> l1p GEMM.
// Grid (8 kq, 4 jq, 16 nb) = 512 blocks x 256 thr. Stage Al[8 rows][128 kk]:
// element (n, ss=kq*128+kk) from SUBT (R18 k_comb verbatim math), then the
// R18-verbatim split-K GEMM body -> P1.
// ---------------------------------------------------------------------------
__global__ __launch_bounds__(256) void k_cl1p(const float* __restrict__ W1,
                                              float* __restrict__ ws) {
    const int kq = blockIdx.x;   // 0..7
    const int jq = blockIdx.y;   // 0..3
    const int nb = blockIdx.z;   // 0..15
    const int tid = threadIdx.x;

    __shared__ float4 Al[8][32];  // 8 n-rows x 128 k
    float* Alf = (float*)Al;
    const float2* SUBT = (const float2*)(ws + OFF_SUBT);
#pragma unroll
    for (int i = 0; i < 4; ++i) {
        const int e    = i * 256 + tid;        // 0..1023
        const int rown = e >> 7;               // 0..7
        const int kk   = e & 127;
        const int n    = nb * 8 + rown;
        const int ss   = kq * 128 + kk;
        const int k    = (ss + 1536) & (MR - 1);
        const int km   = ss & 511;
        const float2* F = SUBT + ((size_t)n * 512 + km) * 4;
        float2 X = F[0];                       // r=0: w=1
        const float f1 = (float)k * (1.0f / 2048.0f);   // exact
#pragma unroll
        for (int rr = 1; rr < 4; ++rr) {
            const float2 Fr = F[rr];
            const float fr = (float)rr * f1;
            const float ff = fr - floorf(fr);  // exact
            const float cv = cos_rev(ff), sv = sin_rev(ff);  // w = cv - i*sv
            X.x = fmaf(Fr.x, cv, fmaf(Fr.y, sv, X.x));
            X.y = fmaf(Fr.y, cv, fmaf(-Fr.x, sv, X.y));
        }
        const int sp = ss - 512;
        const float D = DSCALE * __expf(BETA * (float)(sp * sp));
        Alf[e] = sqrtf(fmaf(X.x, X.x, X.y * X.y)) * D;
    }
    __syncthreads();

    // R18-verbatim l1p GEMM body
    const int jl = tid & 127, ng = tid >> 7;
    const int j = jq * 128 + jl;
    const float4* W1v = (const float4*)W1;
    float a0 = 0.f, a1 = 0.f, a2 = 0.f, a3 = 0.f;
#pragma unroll 4
    for (int k4 = 0; k4 < 32; ++k4) {
        const float4 w  = W1v[(size_t)j * 256 + kq * 32 + k4];
        const float4 x0 = Al[ng * 4 + 0][k4];
        const float4 x1 = Al[ng * 4 + 1][k4];
        const float4 x2 = Al[ng * 4 + 2][k4];
        const float4 x3 = Al[ng * 4 + 3][k4];
        a0 = fmaf(x0.x, w.x, fmaf(x0.y, w.y, fmaf(x0.z, w.z, fmaf(x0.w, w.w, a0))));
        a1 = fmaf(x1.x, w.x, fmaf(x1.y, w.y, fmaf(x1.z, w.z, fmaf(x1.w, w.w, a1))));
        a2 = fmaf(x2.x, w.x, fmaf(x2.y, w.y, fmaf(x2.z, w.z, fmaf(x2.w, w.w, a2))));
        a3 = fmaf(x3.x, w.x, fmaf(x3.y, w.y, fmaf(x3.z, w.z, fmaf(x3.w, w.w, a3))));
    }
    float* P1 = ws + OFF_P1;
    const float acc[4] = {a0, a1, a2, a3};
#pragma unroll
    for (int i = 0; i < 4; ++i)
        P1[((size_t)(kq * NN + nb * 8 + ng * 4 + i)) * H1D + j] = acc[i];
}

// ---------------------------------------------------------------------------
// Kernel 3: FUSED MLP tail per batch n (l1c + l2 + l3) — R16 mlp2 verbatim
// (passed in R16). 128 blocks x 1024 thr; small work, acceptable regime.
// ---------------------------------------------------------------------------
__global__ __launch_bounds__(1024) void k_mlp(const float* __restrict__ b1,
                                              const float* __restrict__ W2,
                                              const float* __restrict__ b2,
                                              const float* __restrict__ W3,
                                              const float* __restrict__ b3,
                                              const float* __restrict__ ws,
                                              float* __restrict__ out) {
    const int n   = blockIdx.x;
    const int tid = threadIdx.x;
    const int wid = tid >> 6, lane = tid & 63;

    __shared__ float h1L[H1D];
    __shared__ float h2L[H2D];

    if (tid < H1D) {
        const int j = tid;
        float s = b1[j];
#pragma unroll
        for (int kq = 0; kq < KQN; ++kq)
            s += ws[OFF_P1 + ((size_t)kq * NN + n) * H1D + j];
        h1L[j] = 1.0f / (1.0f + __expf(-s));
    }
    __syncthreads();

    // layer 2: wave wid handles j = wid*8 .. wid*8+7
    {
        const float4* H1v = (const float4*)h1L;
        const float4 ha = H1v[lane], hb = H1v[64 + lane];
#pragma unroll
        for (int q = 0; q < 8; ++q) {
            const int j = wid * 8 + q;
            const float4* W2v = (const float4*)W2 + (size_t)j * 128;
            const float4 wa = W2v[lane], wb = W2v[64 + lane];
            float a = fmaf(wa.x, ha.x, fmaf(wa.y, ha.y, fmaf(wa.z, ha.z, wa.w * ha.w)));
            a = fmaf(wb.x, hb.x, fmaf(wb.y, hb.y, fmaf(wb.z, hb.z, fmaf(wb.w, hb.w, a))));
            a = wave_sum(a);
            if (lane == 0) h2L[j] = 1.0f / (1.0f + __expf(-(a + b2[j])));
        }
    }
    __syncthreads();

    // layer 3: waves 0..7, one output each
    if (wid < OUTD) {
        const float2 w = ((const float2*)W3)[wid * 64 + lane];
        const float2 h = ((const float2*)h2L)[lane];
        float a = fmaf(w.x, h.x, w.y * h.y);
        a = wave_sum(a);
        if (lane == 0) out[n * OUTD + wid] = a + b3[wid];
    }
}

extern "C" void kernel_launch(void* const* d_in, const int* in_sizes, int n_in,
                              void* d_out, int out_size, void* d_ws, size_t ws_size,
                              hipStream_t stream) {
    (void)in_sizes; (void)n_in; (void)out_size; (void)ws_size;
    const float* inp = (const float*)d_in[0];
    const float* W1  = (const float*)d_in[1];
    const float* b1  = (const float*)d_in[2];
    const float* W2  = (const float*)d_in[3];
    const float* b2  = (const float*)d_in[4];
    const float* W3  = (const float*)d_in[5];
    const float* b3  = (const float*)d_in[6];
    float* out = (float*)d_out;
    float* ws  = (float*)d_ws;

    k_sf  <<<dim3(4, NN),    dim3(256),  0, stream>>>(inp, ws);
    k_cl1p<<<dim3(8, 4, 16), dim3(256),  0, stream>>>(W1, ws);
    k_mlp <<<dim3(NN),       dim3(1024), 0, stream>>>(b1, W2, b2, W3, b3, ws, out);
}